// Round 13
// baseline (396.053 us; speedup 1.0000x reference)
//
#include <hip/hip_runtime.h>

typedef short bf16x8 __attribute__((ext_vector_type(8)));
typedef float f32x4 __attribute__((ext_vector_type(4)));

#define EPSV 1e-5f
#define BNUM 32
#define CH 256
#define HW 3136          // 56*56
#define PXT 3684         // 64 front guard + 3364 (58*58) + 256 back guard
#define NCHUNK 32        // 256/8 ic-chunks
#define PERB_SHORTS (NCHUNK*PXT*8)   // shorts per sample in xpad
#define WB_PERB 589824               // weights per sample (elements)

__device__ __forceinline__ unsigned short f2bf(float f) {
  unsigned int u = __float_as_uint(f);
  u += 0x7fffu + ((u >> 16) & 1u);
  return (unsigned short)(u >> 16);
}

__device__ __forceinline__ void gld16(const void* g, void* l) {
  __builtin_amdgcn_global_load_lds((const __attribute__((address_space(1))) void*)g,
                                   (__attribute__((address_space(3))) void*)l,
                                   16, 0, 0);
}

// ---- gap16: 32 blocks (one per b), 512 thr; reads per-block GAP partials
__global__ void k_gap16(const float* __restrict__ part, const float* __restrict__ rw,
                        const float* __restrict__ rb, float* __restrict__ g16) {
  __shared__ float gcs[256];
  int b = blockIdx.x;
  int t = threadIdx.x;
  if (t < 256) {
    const float* p = part + ((size_t)(b * 32 + (t >> 3)) * 8 + (t & 7)) * 16;
    float s = 0.f;
#pragma unroll
    for (int i = 0; i < 14; ++i) s += p[i];
    gcs[t] = s;
  }
  __syncthreads();
  int j = t >> 5;          // 0..15
  int c0 = t & 31;
  const float* w = rw + j * 256;
  float s = 0.f;
#pragma unroll
  for (int k = 0; k < 8; ++k) s += gcs[c0 + k * 32] * w[c0 + k * 32];
  for (int off = 16; off; off >>= 1) s += __shfl_down(s, off, 32);
  if (c0 == 0) g16[b * 16 + j] = s * (1.f / 3136.f) + rb[j];
}

__global__ void k_act(const float* __restrict__ g16,
                      const float* __restrict__ w1w, const float* __restrict__ w1b,
                      const float* __restrict__ w2w, const float* __restrict__ w2b,
                      float* __restrict__ a1, float* __restrict__ a2) {
  int idx = blockIdx.x * 256 + threadIdx.x;       // < 262144
  int which = idx >> 17;
  int r = idx & 131071;
  int b = r >> 12, m = r & 4095;
  const float* w = (which ? w2w : w1w) + m * 16;
  float s = which ? w2b[m] : w1b[m];
  const float* g = g16 + b * 16;
#pragma unroll
  for (int j = 0; j < 16; ++j) s += g[j] * w[j];
  float out = 1.f / (1.f + __expf(-s));
  (which ? a2 : a1)[r] = out;
}

// ---- zero the border/guard zones of both padded buffers
__global__ void k_zero(unsigned short* __restrict__ xp1, unsigned short* __restrict__ xp2) {
  int bc = blockIdx.x;         // b*32+chunk
  int t = threadIdx.x;         // 256
  uint4 z = {0u, 0u, 0u, 0u};
  for (int wbuf = 0; wbuf < 2; ++wbuf) {
    unsigned short* base = (wbuf ? xp2 : xp1) + (size_t)bc * (PXT * 8);
    uint4* p = (uint4*)base;   // one uint4 per px
    if (t < 123) p[t] = z;                       // front guard + row0 + row1/px0
    p[3370 + t] = z;                             // row57 + back guard (part 1)
    if (t < 58) p[3626 + t] = z;                 // back guard (part 2)
    if (t < 56) {                                // px57 of row py, px0 of row py+1
      int e = 64 + (t + 1) * 58 + 57;
      p[e] = z;
      p[e + 1] = z;
    }
  }
}

// ---- x (NCHW f32) -> xpad bf16 + GAP partial sums (per-block, NO global atomics)
// grid (14, 32, 32), block 256 = 4 rows x 64 lanes
__global__ void k_xpad(const float* __restrict__ x, unsigned short* __restrict__ xp,
                       float* __restrict__ part) {
  int y4 = blockIdx.x, ch = blockIdx.y, b = blockIdx.z;
  int t = threadIdx.x;
  int r = t >> 6, l = t & 63;
  int y = y4 * 4 + r;
  bool act = (l < 56);
  int lc = act ? l : 0;
  const float* src = x + ((size_t)(b * 256 + ch * 8)) * HW + y * 56 + lc;
  float v[8];
#pragma unroll
  for (int k = 0; k < 8; ++k) v[k] = act ? src[k * HW] : 0.f;
  if (act) {
    ushort4 lo, hi;
    lo.x = f2bf(v[0]); lo.y = f2bf(v[1]); lo.z = f2bf(v[2]); lo.w = f2bf(v[3]);
    hi.x = f2bf(v[4]); hi.y = f2bf(v[5]); hi.z = f2bf(v[6]); hi.w = f2bf(v[7]);
    unsigned short* dst = xp + ((size_t)(b * NCHUNK + ch)) * (PXT * 8)
                             + (size_t)(64 + (y + 1) * 58 + (l + 1)) * 8;
    *(ushort4*)dst = lo;
    *(ushort4*)(dst + 4) = hi;
  }
  __shared__ float red[4][8];
#pragma unroll
  for (int k = 0; k < 8; ++k) {
    float s = v[k];
    for (int off = 32; off; off >>= 1) s += __shfl_down(s, off, 64);
    if (l == 0) red[r][k] = s;
  }
  __syncthreads();
  if (t < 8)
    part[((size_t)(b * 32 + ch) * 8 + t) * 16 + y4]
        = red[0][t] + red[1][t] + red[2][t] + red[3][t];
}

// ---- per-sample weight gen.
// layout: off = ((kh*8+s)*2 + ocg)*12288 + kc*3072 + (oc&127)*24 + kw*8 + (ic&7)
__global__ void k_wgen(const float* __restrict__ a, const float4* __restrict__ w2,
                       unsigned short* __restrict__ wb) {
  int og = blockIdx.x & 63, bg = blockIdx.x >> 6;
  int t = threadIdx.x;
  for (int it = 0; it < 36; ++it) {
    int wi = it * 256 + t;                 // < 9216
    int oc_l = wi / 2304;
    int r = wi - oc_l * 2304;
    int ic = r / 9;
    int k9 = r - ic * 9;
    int kh = k9 / 3;
    int kw = k9 - kh * 3;
    int oc = og * 4 + oc_l;
    int g = oc * 4 + (ic >> 6);
    int o = (ic & 63) * 9 + k9;
    float4 w4 = w2[g * 576 + o];
    int s_ = ic >> 5, kc_ = (ic >> 3) & 3, icl = ic & 7;
    int ocg_ = oc >> 7, ocl_ = oc & 127;
    size_t off = (size_t)((kh * 8 + s_) * 2 + ocg_) * 12288 + kc_ * 3072 + ocl_ * 24
               + kw * 8 + icl;
#pragma unroll
    for (int bi = 0; bi < 4; ++bi) {
      int b = bg * 4 + bi;
      float4 a4 = *(const float4*)(a + b * 4096 + g * 4);
      float s = w4.x * a4.x + w4.y * a4.y + w4.z * a4.z + w4.w * a4.w;
      wb[(size_t)b * WB_PERB + off] = f2bf(s);
    }
  }
}

// ---- per-sample 3x3 conv: W dbuf counted-vmcnt + X slab + register-pipelined
// kw phases (2 named fragment sets, compiler-counted lgkm waits).
__global__ __launch_bounds__(256, 2)
void k_conv(const unsigned short* __restrict__ xpad,
            const unsigned short* __restrict__ wbuf,
            const float* __restrict__ bgp, const float* __restrict__ bbp,
            const float* __restrict__ bmp, const float* __restrict__ bvp,
            const float* __restrict__ resid,
            unsigned short* __restrict__ outpad,
            float* __restrict__ outf,
            const int mode) {
  __shared__ unsigned short sW[2][12288];   // [kc 4][oc 128][kw 3][ic 8]  24KB each
  __shared__ unsigned short sX[12288];      // [kc 4][px 384][ic 8]        24KB

  const int tid = threadIdx.x;
  const int lane = tid & 63;
  const int wv = tid >> 6;        // wave 0..3
  const int wocg = wv >> 1;       // oc half within block's 128
  const int wpxg = wv & 1;        // px half within block's 224
  const int ocl = lane & 15;
  const int kc = lane >> 4;

  // XCD-aware decode: sample b pinned to XCD b%8
  int rid = blockIdx.x;           // 0..959
  int xcd = rid & 7;
  int j = rid >> 3;               // 0..119
  int b = xcd + 8 * (j / 30);
  int slot = j % 30;
  int bocg = slot & 1;
  int p0 = 58 + (slot >> 1) * 224;   // valid pp range is [59, 3305]

  const unsigned short* xb = xpad + (size_t)b * PERB_SHORTS + 64 * 8;
  const unsigned short* wbb = wbuf + (size_t)b * WB_PERB + bocg * 12288;

  f32x4 acc[4][7];
#pragma unroll
  for (int i = 0; i < 4; ++i)
#pragma unroll
    for (int k = 0; k < 7; ++k)
      acc[i][k] = (f32x4){0.f, 0.f, 0.f, 0.f};

  int cur = 0;

  // W: 24KB per (s,kh) -> 24 x 1KB segs, wave stages 6
  auto STAGE_W = [&](int t, int buf) {
    int s = t / 3;
    int kh = t - s * 3;
    const unsigned short* wsrc = wbb + (size_t)(kh * 8 + s) * 24576;
#pragma unroll
    for (int i = 0; i < 6; ++i) {
      int seg = wv * 6 + i;
      gld16(wsrc + seg * 512 + lane * 8, &sW[buf][seg * 512]);
    }
  };
  // X: 384-px window [p0-59, p0+324], wave = ic-chunk, 6 gld16
  auto STAGE_X = [&](int s) {
    const unsigned short* xs = xb + ((long)(s * 4 + wv) * PXT + p0 - 59) * 8;
#pragma unroll
    for (int i = 0; i < 6; ++i)
      gld16(xs + (i * 64 + lane) * 8, &sX[wv * 3072 + i * 512]);
  };
  // fragment loads for one kw phase (plain LDS reads; compiler emits counted lgkm)
  auto LOADSET = [&](bf16x8 (&af)[4], bf16x8 (&bf)[7], int kh, int kw) {
#pragma unroll
    for (int fm = 0; fm < 4; ++fm)
      af[fm] = *(const bf16x8*)&sW[cur][kc * 3072 + (wocg * 64 + fm * 16 + ocl) * 24 + kw * 8];
#pragma unroll
    for (int fn = 0; fn < 7; ++fn)
      bf[fn] = *(const bf16x8*)&sX[kc * 3072 + (kh * 58 + wpxg * 112 + fn * 16 + ocl + kw) * 8];
  };
  auto CLUSTER = [&](const bf16x8 (&af)[4], const bf16x8 (&bf)[7]) {
    __builtin_amdgcn_s_setprio(1);
#pragma unroll
    for (int fm = 0; fm < 4; ++fm)
#pragma unroll
      for (int fn = 0; fn < 7; ++fn)
        acc[fm][fn] = __builtin_amdgcn_mfma_f32_16x16x32_bf16(af[fm], bf[fn], acc[fm][fn], 0, 0, 0);
    __builtin_amdgcn_s_setprio(0);
  };

  STAGE_X(0);
  STAGE_W(0, 0);

  bf16x8 afA[4], bfA[7], afB[4], bfB[7];
  for (int s8 = 0; s8 < 8; ++s8) {
#pragma unroll
    for (int kh = 0; kh < 3; ++kh) {
      int t = s8 * 3 + kh;
      if (t + 1 < 24) {
        STAGE_W(t + 1, cur ^ 1);                           // in flight across stage
        asm volatile("s_waitcnt vmcnt(6)" ::: "memory");   // W(t) (+X at s8 bound) landed
      } else {
        asm volatile("s_waitcnt vmcnt(0)" ::: "memory");
      }
      __builtin_amdgcn_s_barrier();          // sW[cur]/sX ready block-wide
      __builtin_amdgcn_sched_barrier(0);     // no LDS reads above the barrier
      LOADSET(afA, bfA, kh, 0);
      LOADSET(afB, bfB, kh, 1);              // kw1 set in flight under kw0 MFMAs
      CLUSTER(afA, bfA);                     // kw0
      LOADSET(afA, bfA, kh, 2);              // kw2 set in flight under kw1 MFMAs
      CLUSTER(afB, bfB);                     // kw1
      CLUSTER(afA, bfA);                     // kw2
      __builtin_amdgcn_s_barrier();          // readers done; next stage may overwrite
      if (kh == 2 && s8 + 1 < 8) STAGE_X(s8 + 1);
      cur ^= 1;
    }
  }

  // ---- epilogue: bn scale/shift table reuses sX
  float* scb = (float*)&sX[0];
  if (tid < 128) {
    int oc = bocg * 128 + tid;
    float sc = bgp[oc] * rsqrtf(bvp[oc] + EPSV);
    scb[tid] = sc;
    scb[128 + tid] = bbp[oc] - bmp[oc] * sc;
  }
  __syncthreads();

  const int dpb = wpxg * 112 + ocl;
  if (mode == 1) {
#pragma unroll
    for (int fn = 0; fn < 7; ++fn) {
      int pp = p0 + dpb + fn * 16;
      int py = pp / 58;
      int px = pp - py * 58;
      if (py < 1 || py > 56 || px < 1 || px > 56) continue;
#pragma unroll
      for (int fm = 0; fm < 4; ++fm) {
        int loc = wocg * 64 + fm * 16 + kc * 4;      // oc r=0 within block's 128
        f32x4 v = acc[fm][fn];
        ushort4 w;
        w.x = f2bf(fmaxf(v[0] * scb[loc + 0] + scb[128 + loc + 0], 0.f));
        w.y = f2bf(fmaxf(v[1] * scb[loc + 1] + scb[128 + loc + 1], 0.f));
        w.z = f2bf(fmaxf(v[2] * scb[loc + 2] + scb[128 + loc + 2], 0.f));
        w.w = f2bf(fmaxf(v[3] * scb[loc + 3] + scb[128 + loc + 3], 0.f));
        int ocg_g = bocg * 128 + loc;                // global oc of r=0
        *(ushort4*)&outpad[((size_t)(b * NCHUNK + (ocg_g >> 3))) * (PXT * 8)
                           + (size_t)(64 + pp) * 8 + (ocg_g & 7)] = w;
      }
    }
  } else {
#pragma unroll
    for (int fn = 0; fn < 7; ++fn) {
      int pp = p0 + dpb + fn * 16;
      int py = pp / 58;
      int px = pp - py * 58;
      if (py < 1 || py > 56 || px < 1 || px > 56) continue;
      int obase = (py - 1) * 56 + (px - 1);
#pragma unroll
      for (int fm = 0; fm < 4; ++fm) {
        int loc = wocg * 64 + fm * 16 + kc * 4;
        f32x4 v = acc[fm][fn];
#pragma unroll
        for (int r = 0; r < 4; ++r) {
          int oc = bocg * 128 + loc + r;
          size_t oi = ((size_t)(b * CH + oc)) * HW + obase;
          float tv = v[r] * scb[loc + r] + scb[128 + loc + r] + resid[oi];
          outf[oi] = fmaxf(tv, 0.f);
        }
      }
    }
  }
}

// ---- workspace offsets (bytes)
#define OFF_XP1 ((size_t)0)
#define XP_BYTES ((size_t)BNUM * PERB_SHORTS * 2)
#define OFF_XP2 (OFF_XP1 + XP_BYTES)
#define OFF_WB  (OFF_XP2 + XP_BYTES)
#define WB_BYTES ((size_t)BNUM * WB_PERB * 2)
#define OFF_PART (OFF_WB + WB_BYTES)                 // 32*32*8*16 f32 = 256KB
#define OFF_G16  (OFF_PART + 262144)
#define OFF_A1   (OFF_G16 + 2048)
#define OFF_A2   (OFF_A1 + 524288)

extern "C" void kernel_launch(void* const* d_in, const int* in_sizes, int n_in,
                              void* d_out, int out_size, void* d_ws, size_t ws_size,
                              hipStream_t stream) {
  (void)in_sizes; (void)n_in; (void)out_size; (void)ws_size;
  const float* x        = (const float*)d_in[0];
  const float* reduce_w = (const float*)d_in[1];
  const float* reduce_b = (const float*)d_in[2];
  const float* w1fc1w   = (const float*)d_in[3];
  const float* w1fc1b   = (const float*)d_in[4];
  const float* w1fc2w   = (const float*)d_in[5];
  const float* bn1g     = (const float*)d_in[6];
  const float* bn1b     = (const float*)d_in[7];
  const float* bn1m     = (const float*)d_in[8];
  const float* bn1v     = (const float*)d_in[9];
  const float* w2fc1w   = (const float*)d_in[10];
  const float* w2fc1b   = (const float*)d_in[11];
  const float* w2fc2w   = (const float*)d_in[12];
  const float* bn2g     = (const float*)d_in[13];
  const float* bn2b     = (const float*)d_in[14];
  const float* bn2m     = (const float*)d_in[15];
  const float* bn2v     = (const float*)d_in[16];

  char* ws = (char*)d_ws;
  unsigned short* xp1 = (unsigned short*)(ws + OFF_XP1);
  unsigned short* xp2 = (unsigned short*)(ws + OFF_XP2);
  unsigned short* wb  = (unsigned short*)(ws + OFF_WB);
  float* part = (float*)(ws + OFF_PART);
  float* g16  = (float*)(ws + OFF_G16);
  float* a1   = (float*)(ws + OFF_A1);
  float* a2   = (float*)(ws + OFF_A2);
  float* outf = (float*)d_out;

  k_zero<<<1024, 256, 0, stream>>>(xp1, xp2);
  k_xpad<<<dim3(14, NCHUNK, BNUM), 256, 0, stream>>>(x, xp1, part);
  k_gap16<<<BNUM, 512, 0, stream>>>(part, reduce_w, reduce_b, g16);
  k_act<<<1024, 256, 0, stream>>>(g16, w1fc1w, w1fc1b, w2fc1w, w2fc1b, a1, a2);

  k_wgen<<<512, 256, 0, stream>>>(a1, (const float4*)w1fc2w, wb);
  k_conv<<<960, 256, 0, stream>>>(xp1, wb, bn1g, bn1b, bn1m, bn1v,
                                  nullptr, xp2, nullptr, 1);
  k_wgen<<<512, 256, 0, stream>>>(a2, (const float4*)w2fc2w, wb);
  k_conv<<<960, 256, 0, stream>>>(xp2, wb, bn2g, bn2b, bn2m, bn2v,
                                  x, nullptr, outf, 2);
}

// Round 15
// 395.463 us; speedup vs baseline: 1.0015x; 1.0015x over previous
//
#include <hip/hip_runtime.h>

typedef short bf16x8 __attribute__((ext_vector_type(8)));
typedef float f32x4 __attribute__((ext_vector_type(4)));

#define EPSV 1e-5f
#define BNUM 32
#define CH 256
#define HW 3136          // 56*56
#define PXT 3684         // 64 front guard + 3364 (58*58) + 256 back guard
#define NCHUNK 32        // 256/8 ic-chunks
#define PERB_SHORTS (NCHUNK*PXT*8)   // shorts per sample in xpad
#define WB_PERB 589824               // weights per sample (elements)

__device__ __forceinline__ unsigned short f2bf(float f) {
  unsigned int u = __float_as_uint(f);
  u += 0x7fffu + ((u >> 16) & 1u);
  return (unsigned short)(u >> 16);
}

__device__ __forceinline__ void gld16(const void* g, void* l) {
  __builtin_amdgcn_global_load_lds((const __attribute__((address_space(1))) void*)g,
                                   (__attribute__((address_space(3))) void*)l,
                                   16, 0, 0);
}

// ---- gap16: 32 blocks (one per b), 512 thr; reads per-block GAP partials
__global__ void k_gap16(const float* __restrict__ part, const float* __restrict__ rw,
                        const float* __restrict__ rb, float* __restrict__ g16) {
  __shared__ float gcs[256];
  int b = blockIdx.x;
  int t = threadIdx.x;
  if (t < 256) {
    const float* p = part + ((size_t)(b * 32 + (t >> 3)) * 8 + (t & 7)) * 16;
    float s = 0.f;
#pragma unroll
    for (int i = 0; i < 14; ++i) s += p[i];
    gcs[t] = s;
  }
  __syncthreads();
  int j = t >> 5;          // 0..15
  int c0 = t & 31;
  const float* w = rw + j * 256;
  float s = 0.f;
#pragma unroll
  for (int k = 0; k < 8; ++k) s += gcs[c0 + k * 32] * w[c0 + k * 32];
  for (int off = 16; off; off >>= 1) s += __shfl_down(s, off, 32);
  if (c0 == 0) g16[b * 16 + j] = s * (1.f / 3136.f) + rb[j];
}

__global__ void k_act(const float* __restrict__ g16,
                      const float* __restrict__ w1w, const float* __restrict__ w1b,
                      const float* __restrict__ w2w, const float* __restrict__ w2b,
                      float* __restrict__ a1, float* __restrict__ a2) {
  int idx = blockIdx.x * 256 + threadIdx.x;       // < 262144
  int which = idx >> 17;
  int r = idx & 131071;
  int b = r >> 12, m = r & 4095;
  const float* w = (which ? w2w : w1w) + m * 16;
  float s = which ? w2b[m] : w1b[m];
  const float* g = g16 + b * 16;
#pragma unroll
  for (int j = 0; j < 16; ++j) s += g[j] * w[j];
  float out = 1.f / (1.f + __expf(-s));
  (which ? a2 : a1)[r] = out;
}

// ---- zero the border/guard zones of both padded buffers
__global__ void k_zero(unsigned short* __restrict__ xp1, unsigned short* __restrict__ xp2) {
  int bc = blockIdx.x;         // b*32+chunk
  int t = threadIdx.x;         // 256
  uint4 z = {0u, 0u, 0u, 0u};
  for (int wbuf = 0; wbuf < 2; ++wbuf) {
    unsigned short* base = (wbuf ? xp2 : xp1) + (size_t)bc * (PXT * 8);
    uint4* p = (uint4*)base;   // one uint4 per px
    if (t < 123) p[t] = z;                       // front guard + row0 + row1/px0
    p[3370 + t] = z;                             // row57 + back guard (part 1)
    if (t < 58) p[3626 + t] = z;                 // back guard (part 2)
    if (t < 56) {                                // px57 of row py, px0 of row py+1
      int e = 64 + (t + 1) * 58 + 57;
      p[e] = z;
      p[e + 1] = z;
    }
  }
}

// ---- x (NCHW f32) -> xpad bf16 + GAP partial sums (per-block, NO global atomics)
// grid (14, 32, 32), block 256 = 4 rows x 64 lanes
__global__ void k_xpad(const float* __restrict__ x, unsigned short* __restrict__ xp,
                       float* __restrict__ part) {
  int y4 = blockIdx.x, ch = blockIdx.y, b = blockIdx.z;
  int t = threadIdx.x;
  int r = t >> 6, l = t & 63;
  int y = y4 * 4 + r;
  bool act = (l < 56);
  int lc = act ? l : 0;
  const float* src = x + ((size_t)(b * 256 + ch * 8)) * HW + y * 56 + lc;
  float v[8];
#pragma unroll
  for (int k = 0; k < 8; ++k) v[k] = act ? src[k * HW] : 0.f;
  if (act) {
    ushort4 lo, hi;
    lo.x = f2bf(v[0]); lo.y = f2bf(v[1]); lo.z = f2bf(v[2]); lo.w = f2bf(v[3]);
    hi.x = f2bf(v[4]); hi.y = f2bf(v[5]); hi.z = f2bf(v[6]); hi.w = f2bf(v[7]);
    unsigned short* dst = xp + ((size_t)(b * NCHUNK + ch)) * (PXT * 8)
                             + (size_t)(64 + (y + 1) * 58 + (l + 1)) * 8;
    *(ushort4*)dst = lo;
    *(ushort4*)(dst + 4) = hi;
  }
  __shared__ float red[4][8];
#pragma unroll
  for (int k = 0; k < 8; ++k) {
    float s = v[k];
    for (int off = 32; off; off >>= 1) s += __shfl_down(s, off, 64);
    if (l == 0) red[r][k] = s;
  }
  __syncthreads();
  if (t < 8)
    part[((size_t)(b * 32 + ch) * 8 + t) * 16 + y4]
        = red[0][t] + red[1][t] + red[2][t] + red[3][t];
}

// ---- per-sample weight gen.
// layout: off = ((kh*8+s)*2 + ocg)*12288 + kc*3072 + (oc&127)*24 + kw*8 + (ic&7)
__global__ void k_wgen(const float* __restrict__ a, const float4* __restrict__ w2,
                       unsigned short* __restrict__ wb) {
  int og = blockIdx.x & 63, bg = blockIdx.x >> 6;
  int t = threadIdx.x;
  for (int it = 0; it < 36; ++it) {
    int wi = it * 256 + t;                 // < 9216
    int oc_l = wi / 2304;
    int r = wi - oc_l * 2304;
    int ic = r / 9;
    int k9 = r - ic * 9;
    int kh = k9 / 3;
    int kw = k9 - kh * 3;
    int oc = og * 4 + oc_l;
    int g = oc * 4 + (ic >> 6);
    int o = (ic & 63) * 9 + k9;
    float4 w4 = w2[g * 576 + o];
    int s_ = ic >> 5, kc_ = (ic >> 3) & 3, icl = ic & 7;
    int ocg_ = oc >> 7, ocl_ = oc & 127;
    size_t off = (size_t)((kh * 8 + s_) * 2 + ocg_) * 12288 + kc_ * 3072 + ocl_ * 24
               + kw * 8 + icl;
#pragma unroll
    for (int bi = 0; bi < 4; ++bi) {
      int b = bg * 4 + bi;
      float4 a4 = *(const float4*)(a + b * 4096 + g * 4);
      float s = w4.x * a4.x + w4.y * a4.y + w4.z * a4.z + w4.w * a4.w;
      wb[(size_t)b * WB_PERB + off] = f2bf(s);
    }
  }
}

// ---- per-sample 3x3 conv: W dbuf counted-vmcnt + X slab + register-pipelined
// kw phases (2 named fragment sets, compiler-counted lgkm waits). [R13 champion]
__global__ __launch_bounds__(256, 2)
void k_conv(const unsigned short* __restrict__ xpad,
            const unsigned short* __restrict__ wbuf,
            const float* __restrict__ bgp, const float* __restrict__ bbp,
            const float* __restrict__ bmp, const float* __restrict__ bvp,
            const float* __restrict__ resid,
            unsigned short* __restrict__ outpad,
            float* __restrict__ outf,
            const int mode) {
  __shared__ unsigned short sW[2][12288];   // [kc 4][oc 128][kw 3][ic 8]  24KB each
  __shared__ unsigned short sX[12288];      // [kc 4][px 384][ic 8]        24KB

  const int tid = threadIdx.x;
  const int lane = tid & 63;
  const int wv = tid >> 6;        // wave 0..3
  const int wocg = wv >> 1;       // oc half within block's 128
  const int wpxg = wv & 1;        // px half within block's 224
  const int ocl = lane & 15;
  const int kc = lane >> 4;

  // XCD-aware decode: sample b pinned to XCD b%8
  int rid = blockIdx.x;           // 0..959
  int xcd = rid & 7;
  int j = rid >> 3;               // 0..119
  int b = xcd + 8 * (j / 30);
  int slot = j % 30;
  int bocg = slot & 1;
  int p0 = 58 + (slot >> 1) * 224;   // valid pp range is [59, 3305]

  const unsigned short* xb = xpad + (size_t)b * PERB_SHORTS + 64 * 8;
  const unsigned short* wbb = wbuf + (size_t)b * WB_PERB + bocg * 12288;

  f32x4 acc[4][7];
#pragma unroll
  for (int i = 0; i < 4; ++i)
#pragma unroll
    for (int k = 0; k < 7; ++k)
      acc[i][k] = (f32x4){0.f, 0.f, 0.f, 0.f};

  int cur = 0;

  // W: 24KB per (s,kh) -> 24 x 1KB segs, wave stages 6
  auto STAGE_W = [&](int t, int buf) {
    int s = t / 3;
    int kh = t - s * 3;
    const unsigned short* wsrc = wbb + (size_t)(kh * 8 + s) * 24576;
#pragma unroll
    for (int i = 0; i < 6; ++i) {
      int seg = wv * 6 + i;
      gld16(wsrc + seg * 512 + lane * 8, &sW[buf][seg * 512]);
    }
  };
  // X: 384-px window [p0-59, p0+324], wave = ic-chunk, 6 gld16
  auto STAGE_X = [&](int s) {
    const unsigned short* xs = xb + ((long)(s * 4 + wv) * PXT + p0 - 59) * 8;
#pragma unroll
    for (int i = 0; i < 6; ++i)
      gld16(xs + (i * 64 + lane) * 8, &sX[wv * 3072 + i * 512]);
  };
  // fragment loads for one kw phase (plain LDS reads; compiler emits counted lgkm)
  auto LOADSET = [&](bf16x8 (&af)[4], bf16x8 (&bf)[7], int kh, int kw) {
#pragma unroll
    for (int fm = 0; fm < 4; ++fm)
      af[fm] = *(const bf16x8*)&sW[cur][kc * 3072 + (wocg * 64 + fm * 16 + ocl) * 24 + kw * 8];
#pragma unroll
    for (int fn = 0; fn < 7; ++fn)
      bf[fn] = *(const bf16x8*)&sX[kc * 3072 + (kh * 58 + wpxg * 112 + fn * 16 + ocl + kw) * 8];
  };
  auto CLUSTER = [&](const bf16x8 (&af)[4], const bf16x8 (&bf)[7]) {
    __builtin_amdgcn_s_setprio(1);
#pragma unroll
    for (int fm = 0; fm < 4; ++fm)
#pragma unroll
      for (int fn = 0; fn < 7; ++fn)
        acc[fm][fn] = __builtin_amdgcn_mfma_f32_16x16x32_bf16(af[fm], bf[fn], acc[fm][fn], 0, 0, 0);
    __builtin_amdgcn_s_setprio(0);
  };

  STAGE_X(0);
  STAGE_W(0, 0);

  bf16x8 afA[4], bfA[7], afB[4], bfB[7];
  for (int s8 = 0; s8 < 8; ++s8) {
#pragma unroll
    for (int kh = 0; kh < 3; ++kh) {
      int t = s8 * 3 + kh;
      if (t + 1 < 24) {
        STAGE_W(t + 1, cur ^ 1);                           // in flight across stage
        asm volatile("s_waitcnt vmcnt(6)" ::: "memory");   // W(t) (+X at s8 bound) landed
      } else {
        asm volatile("s_waitcnt vmcnt(0)" ::: "memory");
      }
      __builtin_amdgcn_s_barrier();          // sW[cur]/sX ready block-wide
      __builtin_amdgcn_sched_barrier(0);     // no LDS reads above the barrier
      LOADSET(afA, bfA, kh, 0);
      LOADSET(afB, bfB, kh, 1);              // kw1 set in flight under kw0 MFMAs
      CLUSTER(afA, bfA);                     // kw0
      LOADSET(afA, bfA, kh, 2);              // kw2 set in flight under kw1 MFMAs
      CLUSTER(afB, bfB);                     // kw1
      CLUSTER(afA, bfA);                     // kw2
      __builtin_amdgcn_s_barrier();          // readers done; next stage may overwrite
      if (kh == 2 && s8 + 1 < 8) STAGE_X(s8 + 1);
      cur ^= 1;
    }
  }

  // ---- epilogue: bn scale/shift table reuses sX
  float* scb = (float*)&sX[0];
  if (tid < 128) {
    int oc = bocg * 128 + tid;
    float sc = bgp[oc] * rsqrtf(bvp[oc] + EPSV);
    scb[tid] = sc;
    scb[128 + tid] = bbp[oc] - bmp[oc] * sc;
  }
  __syncthreads();

  const int dpb = wpxg * 112 + ocl;
  if (mode == 1) {
#pragma unroll
    for (int fn = 0; fn < 7; ++fn) {
      int pp = p0 + dpb + fn * 16;
      int py = pp / 58;
      int px = pp - py * 58;
      if (py < 1 || py > 56 || px < 1 || px > 56) continue;
#pragma unroll
      for (int fm = 0; fm < 4; ++fm) {
        int loc = wocg * 64 + fm * 16 + kc * 4;      // oc r=0 within block's 128
        f32x4 v = acc[fm][fn];
        ushort4 w;
        w.x = f2bf(fmaxf(v[0] * scb[loc + 0] + scb[128 + loc + 0], 0.f));
        w.y = f2bf(fmaxf(v[1] * scb[loc + 1] + scb[128 + loc + 1], 0.f));
        w.z = f2bf(fmaxf(v[2] * scb[loc + 2] + scb[128 + loc + 2], 0.f));
        w.w = f2bf(fmaxf(v[3] * scb[loc + 3] + scb[128 + loc + 3], 0.f));
        int ocg_g = bocg * 128 + loc;                // global oc of r=0
        *(ushort4*)&outpad[((size_t)(b * NCHUNK + (ocg_g >> 3))) * (PXT * 8)
                           + (size_t)(64 + pp) * 8 + (ocg_g & 7)] = w;
      }
    }
  } else {
#pragma unroll
    for (int fn = 0; fn < 7; ++fn) {
      int pp = p0 + dpb + fn * 16;
      int py = pp / 58;
      int px = pp - py * 58;
      if (py < 1 || py > 56 || px < 1 || px > 56) continue;
      int obase = (py - 1) * 56 + (px - 1);
#pragma unroll
      for (int fm = 0; fm < 4; ++fm) {
        int loc = wocg * 64 + fm * 16 + kc * 4;
        f32x4 v = acc[fm][fn];
#pragma unroll
        for (int r = 0; r < 4; ++r) {
          int oc = bocg * 128 + loc + r;
          size_t oi = ((size_t)(b * CH + oc)) * HW + obase;
          float tv = v[r] * scb[loc + r] + scb[128 + loc + r] + resid[oi];
          outf[oi] = fmaxf(tv, 0.f);
        }
      }
    }
  }
}

// ---- workspace offsets (bytes)
#define OFF_XP1 ((size_t)0)
#define XP_BYTES ((size_t)BNUM * PERB_SHORTS * 2)
#define OFF_XP2 (OFF_XP1 + XP_BYTES)
#define OFF_WB  (OFF_XP2 + XP_BYTES)
#define WB_BYTES ((size_t)BNUM * WB_PERB * 2)
#define OFF_PART (OFF_WB + WB_BYTES)                 // 32*32*8*16 f32 = 256KB
#define OFF_G16  (OFF_PART + 262144)
#define OFF_A1   (OFF_G16 + 2048)
#define OFF_A2   (OFF_A1 + 524288)

extern "C" void kernel_launch(void* const* d_in, const int* in_sizes, int n_in,
                              void* d_out, int out_size, void* d_ws, size_t ws_size,
                              hipStream_t stream) {
  (void)in_sizes; (void)n_in; (void)out_size; (void)ws_size;
  const float* x        = (const float*)d_in[0];
  const float* reduce_w = (const float*)d_in[1];
  const float* reduce_b = (const float*)d_in[2];
  const float* w1fc1w   = (const float*)d_in[3];
  const float* w1fc1b   = (const float*)d_in[4];
  const float* w1fc2w   = (const float*)d_in[5];
  const float* bn1g     = (const float*)d_in[6];
  const float* bn1b     = (const float*)d_in[7];
  const float* bn1m     = (const float*)d_in[8];
  const float* bn1v     = (const float*)d_in[9];
  const float* w2fc1w   = (const float*)d_in[10];
  const float* w2fc1b   = (const float*)d_in[11];
  const float* w2fc2w   = (const float*)d_in[12];
  const float* bn2g     = (const float*)d_in[13];
  const float* bn2b     = (const float*)d_in[14];
  const float* bn2m     = (const float*)d_in[15];
  const float* bn2v     = (const float*)d_in[16];

  char* ws = (char*)d_ws;
  unsigned short* xp1 = (unsigned short*)(ws + OFF_XP1);
  unsigned short* xp2 = (unsigned short*)(ws + OFF_XP2);
  unsigned short* wb  = (unsigned short*)(ws + OFF_WB);
  float* part = (float*)(ws + OFF_PART);
  float* g16  = (float*)(ws + OFF_G16);
  float* a1   = (float*)(ws + OFF_A1);
  float* a2   = (float*)(ws + OFF_A2);
  float* outf = (float*)d_out;

  k_zero<<<1024, 256, 0, stream>>>(xp1, xp2);
  k_xpad<<<dim3(14, NCHUNK, BNUM), 256, 0, stream>>>(x, xp1, part);
  k_gap16<<<BNUM, 512, 0, stream>>>(part, reduce_w, reduce_b, g16);
  k_act<<<1024, 256, 0, stream>>>(g16, w1fc1w, w1fc1b, w2fc1w, w2fc1b, a1, a2);

  k_wgen<<<512, 256, 0, stream>>>(a1, (const float4*)w1fc2w, wb);
  k_conv<<<960, 256, 0, stream>>>(xp1, wb, bn1g, bn1b, bn1m, bn1v,
                                  nullptr, xp2, nullptr, 1);
  k_wgen<<<512, 256, 0, stream>>>(a2, (const float4*)w2fc2w, wb);
  k_conv<<<960, 256, 0, stream>>>(xp2, wb, bn2g, bn2b, bn2m, bn2v,
                                  x, nullptr, outf, 2);
}